// Round 18
// baseline (360.513 us; speedup 1.0000x reference)
//
#include <hip/hip_runtime.h>
#include <stdint.h>

typedef unsigned short ushort_t;
typedef __attribute__((ext_vector_type(8))) short bf16x8;   // 8 bf16 in 4 VGPRs
typedef __attribute__((ext_vector_type(4))) float f32x4;
typedef __attribute__((ext_vector_type(4))) unsigned short us4;

#define DEV __device__ __forceinline__

DEV unsigned short f2bf(float f) {           // RNE f32 -> bf16
  union { float f; unsigned u; } x; x.f = f;
  unsigned r = x.u + 0x7fffu + ((x.u >> 16) & 1u);
  return (unsigned short)(r >> 16);
}

DEV float bf2f(unsigned short u) {
  union { unsigned u; float f; } x; x.u = (unsigned)u << 16; return x.f;
}

DEV uint2 pk4(float v0, float v1, float v2, float v3) {  // 4 f32 -> 4 bf16 (RNE)
  unsigned d0, d1;
  asm("v_cvt_pk_bf16_f32 %0, %1, %2" : "=v"(d0) : "v"(v0), "v"(v1));
  asm("v_cvt_pk_bf16_f32 %0, %1, %2" : "=v"(d1) : "v"(v2), "v"(v3));
  uint2 r; r.x = d0; r.y = d1; return r;
}

DEV void gload16(const void* g, void* l) {   // async global->LDS, 16B/lane
  __builtin_amdgcn_global_load_lds(
      (const __attribute__((address_space(1))) unsigned int*)g,
      (__attribute__((address_space(3))) unsigned int*)l, 16, 0, 0);
}

#define MFMA16 __builtin_amdgcn_mfma_f32_16x16x32_bf16

// ---------------------------------------------------------------- casts
// fused: blocks [0,4096) cast x0->y0, [4096,8192) cast x1->y1
__global__ __launch_bounds__(256) void cast2_bf16_kernel(
    const float* __restrict__ x0, ushort_t* __restrict__ y0,
    const float* __restrict__ x1, ushort_t* __restrict__ y1) {
  int blk = blockIdx.x;
  const float* x = (blk < 4096) ? x0 : x1;
  ushort_t* y = (blk < 4096) ? y0 : y1;
  int i = (blk & 4095) * 256 + threadIdx.x;
  float4 v = ((const float4*)x)[i];
  us4 o; o.x = f2bf(v.x); o.y = f2bf(v.y); o.z = f2bf(v.z); o.w = f2bf(v.w);
  ((us4*)y)[i] = o;
}

// y[i] = bf16(p0[i] + p1[i])  (bf16 split-K partials)
__global__ __launch_bounds__(256) void reduce_cast_kernel(
    const ushort_t* __restrict__ p0, const ushort_t* __restrict__ p1,
    ushort_t* __restrict__ y, int n4) {
  int i = blockIdx.x * 256 + threadIdx.x;
  if (i >= n4) return;
  us4 a = ((const us4*)p0)[i];
  us4 b = ((const us4*)p1)[i];
  us4 o;
  o.x = f2bf(bf2f(a.x) + bf2f(b.x));
  o.y = f2bf(bf2f(a.y) + bf2f(b.y));
  o.z = f2bf(bf2f(a.z) + bf2f(b.z));
  o.w = f2bf(bf2f(a.w) + bf2f(b.w));
  ((us4*)y)[i] = o;
}

// W[K,N] f32 -> Wt[N,K] bf16 (generic dims)
__global__ __launch_bounds__(256) void transpose_cast_kernel(
    const float* __restrict__ W, ushort_t* __restrict__ dst, int K, int N) {
  __shared__ float tile[64][65];
  int n0 = blockIdx.x * 64, k0 = blockIdx.y * 64;
  int tid = threadIdx.x;
#pragma unroll
  for (int it = 0; it < 16; ++it) {
    int idx = it * 256 + tid; int r = idx >> 6, c = idx & 63;
    tile[r][c] = W[(size_t)(k0 + r) * N + n0 + c];
  }
  __syncthreads();
#pragma unroll
  for (int it = 0; it < 16; ++it) {
    int idx = it * 256 + tid; int r = idx >> 6, c = idx & 63;
    dst[(size_t)(n0 + r) * K + k0 + c] = f2bf(tile[c][r]);
  }
}

struct Src8 { const float* p[8]; };
// 8x fused 1024x1024 weight transposes (one launch)
__global__ __launch_bounds__(256) void transpose_cast8_kernel(
    Src8 s, ushort_t* __restrict__ dst) {
  __shared__ float tile[64][65];
  const float* W = s.p[blockIdx.z];
  ushort_t* out = dst + (size_t)blockIdx.z * 1048576;
  int n0 = blockIdx.x * 64, k0 = blockIdx.y * 64;
  int tid = threadIdx.x;
#pragma unroll
  for (int it = 0; it < 16; ++it) {
    int idx = it * 256 + tid; int r = idx >> 6, c = idx & 63;
    tile[r][c] = W[(size_t)(k0 + r) * 1024 + n0 + c];
  }
  __syncthreads();
#pragma unroll
  for (int it = 0; it < 16; ++it) {
    int idx = it * 256 + tid; int r = idx >> 6, c = idx & 63;
    out[(size_t)(n0 + r) * 1024 + k0 + c] = f2bf(tile[c][r]);
  }
}

// V [B,S,(ldv)] head-cols -> vT [B*H, 64, 1024]   (us4-vectorized global I/O)
__global__ __launch_bounds__(256) void transpose_v_kernel(
    const ushort_t* __restrict__ V, int ldv, ushort_t* __restrict__ vT) {
  __shared__ ushort_t tile[64][65];
  int s0 = blockIdx.x * 64;
  int bh = blockIdx.y;
  int b = bh >> 4, h = bh & 15;
  int tid = threadIdx.x;
#pragma unroll
  for (int it = 0; it < 4; ++it) {
    int idx = it * 256 + tid; int r = idx >> 4, c = (idx & 15) * 4;
    us4 v = *(const us4*)&V[(size_t)(b * 1024 + s0 + r) * ldv + h * 64 + c];
    tile[r][c] = v.x; tile[r][c + 1] = v.y; tile[r][c + 2] = v.z; tile[r][c + 3] = v.w;
  }
  __syncthreads();
#pragma unroll
  for (int it = 0; it < 4; ++it) {
    int idx = it * 256 + tid; int r = idx >> 4, c = (idx & 15) * 4;
    us4 o; o.x = tile[c][r]; o.y = tile[c + 1][r]; o.z = tile[c + 2][r]; o.w = tile[c + 3][r];
    *(us4*)&vT[((size_t)bh * 64 + r) * 1024 + s0 + c] = o;
  }
}

// ---------------------------------------------------------------- GEMM 128^2
// OPERAND-SWAPPED MFMA: acc[m][n] = mfma(bF_n, aF_m) => lane holds 4
// CONSECUTIVE output cols (reg j) of row ..+lrow -> 8B dwordx2 C-stores.
template <int RELU>
__global__ __launch_bounds__(256, 2) void gemm_bt(
    const ushort_t* __restrict__ A, const ushort_t* __restrict__ Bt,
    const float* __restrict__ b0, const float* __restrict__ b1,
    const float* __restrict__ b2, const float* __restrict__ b3,
    ushort_t* __restrict__ Cb, int M, int N, int K, int Ks, long long pstr) {
  __shared__ ushort_t sA[4096];  // [128][32] bf16, 8KB
  __shared__ ushort_t sB[4096];
  const int tid = threadIdx.x;
  const int w = tid >> 6, lane = tid & 63;
  const int lrow = lane & 15, lk = lane >> 4;
  const int m0 = blockIdx.x * 128, n0 = blockIdx.y * 128;
  const int kz = blockIdx.z * Ks;
  const int wr = w >> 1, wc = w & 1;
  f32x4 acc[4][4] = {};
  const int brow0 = (w * 1024 + lane * 16) >> 6;  // row for sweep 0
  const int kbyte = (lane * 16) & 63;             // byte within 64B row

  for (int kt = kz; kt < kz + Ks; kt += 32) {
    __syncthreads();
    const ushort_t* ga = A + (size_t)(m0 + brow0) * K + kt + (kbyte >> 1);
    gload16(ga, (char*)sA + w * 1024);
    gload16(ga + (size_t)64 * K, (char*)sA + 4096 + w * 1024);
    const ushort_t* gb = Bt + (size_t)(n0 + brow0) * K + kt + (kbyte >> 1);
    gload16(gb, (char*)sB + w * 1024);
    gload16(gb + (size_t)64 * K, (char*)sB + 4096 + w * 1024);
    __syncthreads();
    bf16x8 aF[4], bF[4];
#pragma unroll
    for (int t = 0; t < 4; ++t) {
      bF[t] = *(const bf16x8*)((const char*)sB + ((wc * 64 + t * 16 + lrow) << 6) + (lk << 4));
      aF[t] = *(const bf16x8*)((const char*)sA + ((wr * 64 + t * 16 + lrow) << 6) + (lk << 4));
    }
#pragma unroll
    for (int mt = 0; mt < 4; ++mt)
#pragma unroll
      for (int nt = 0; nt < 4; ++nt)
        acc[mt][nt] = MFMA16(bF[nt], aF[mt], acc[mt][nt], 0, 0, 0);
  }
  ushort_t* Cbz = Cb + (long long)blockIdx.z * pstr;
#pragma unroll
  for (int nt = 0; nt < 4; ++nt) {
    int colb = n0 + wc * 64 + nt * 16 + lk * 4;   // 4 consecutive cols
    int seg = colb >> 10;
    const float* bp = seg == 0 ? b0 : seg == 1 ? b1 : seg == 2 ? b2 : b3;
    float4 bv = *(const float4*)(bp + (colb & 1023));
    if (blockIdx.z != 0) { bv.x = bv.y = bv.z = bv.w = 0.f; }
#pragma unroll
    for (int mt = 0; mt < 4; ++mt) {
      int row = m0 + wr * 64 + mt * 16 + lrow;
      float v0 = acc[mt][nt][0] + bv.x, v1 = acc[mt][nt][1] + bv.y;
      float v2 = acc[mt][nt][2] + bv.z, v3 = acc[mt][nt][3] + bv.w;
      if (RELU) {
        v0 = fmaxf(v0, 0.f); v1 = fmaxf(v1, 0.f);
        v2 = fmaxf(v2, 0.f); v3 = fmaxf(v3, 0.f);
      }
      *(uint2*)&Cbz[(size_t)row * N + colb] = pk4(v0, v1, v2, v3);
    }
  }
}

// ---------------------------------------------------------------- GEMM 256^2
// SINGLE-BARRIER-PER-TILE (R12-verified). Swizzle byte ^= (row&7)<<4 both
// sides (0 conflicts). Operand-swapped MFMA => vectorized 8B C-stores.
template <int RELU>
__global__ __launch_bounds__(512, 1) void gemm256(
    const ushort_t* __restrict__ A, const ushort_t* __restrict__ Bt,
    const float* __restrict__ b0, const float* __restrict__ b1,
    const float* __restrict__ b2, const float* __restrict__ b3,
    ushort_t* __restrict__ Cb, int M, int N, int K, int Ks, long long pstr) {
  extern __shared__ char L[];  // 131072 bytes
  const int tid = threadIdx.x;
  const int w = tid >> 6, lane = tid & 63;
  const int lrow = lane & 15, lk = lane >> 4;
  const int wm = w >> 2, wn = w & 3;
  const int m0 = blockIdx.x * 256, n0 = blockIdx.y * 256;
  const int kz = blockIdx.z * Ks;
  const int nt = Ks >> 6;

  const int srow = w * 8 + (lane >> 3);
  const int gsw = (lane & 7) ^ ((lane >> 3) & 7);
  const ushort_t* srcA = A + (size_t)(m0 + srow) * K + kz + gsw * 8;
  const ushort_t* srcB = Bt + (size_t)(n0 + srow) * K + kz + gsw * 8;
  const int dstw = w * 1024;

  // stage whole matrix M_ (0=A,1=B) of tile T_ (4 gloads, sweeps 0..3)
#define STG4(M_, T_)                                                  \
  do {                                                                \
    const ushort_t* g0 = ((M_) ? srcB : srcA) + (size_t)(T_) * 64;    \
    char* d_ = L + (((T_) & 1) << 16) + ((M_) << 15) + dstw;          \
    gload16(g0, d_);                                                  \
    gload16(g0 + (size_t)64 * K, d_ + 8192);                          \
    gload16(g0 + (size_t)128 * K, d_ + 16384);                        \
    gload16(g0 + (size_t)192 * K, d_ + 24576);                        \
  } while (0)

  f32x4 acc[8][4] = {};
  const int swz = (lrow & 7) << 4;
  const int k0b = (lk << 4) ^ swz;          // kk=0 byte within 128B row
  const int k1b = (64 + (lk << 4)) ^ swz;   // kk=1
  const int aBase = (wm * 128 + lrow) << 7;           // + m*2048
  const int bBase = ((wn * 64 + lrow) << 7) + 32768;  // + n*2048

  // ---- prologue: tile 0 fully staged
  STG4(0, 0); STG4(1, 0);
  asm volatile("s_waitcnt vmcnt(0)" ::: "memory");
  __builtin_amdgcn_s_barrier();

  for (int t = 0; t < nt; ++t) {
    const char* base = L + ((t & 1) << 16);
    bf16x8 aF[8], bF[4];
    if (t + 1 < nt) STG4(1, t + 1);            // B(t+1) -> buf^1 (early)
    // ---- kk0: 12 reads then 32 MFMA (counted lgkm overlaps them)
#pragma unroll
    for (int n = 0; n < 4; ++n) bF[n] = *(const bf16x8*)(base + bBase + n * 2048 + k0b);
#pragma unroll
    for (int m = 0; m < 8; ++m) aF[m] = *(const bf16x8*)(base + aBase + m * 2048 + k0b);
    __builtin_amdgcn_s_setprio(1);
#pragma unroll
    for (int m = 0; m < 8; ++m)
#pragma unroll
      for (int n = 0; n < 4; ++n)
        acc[m][n] = MFMA16(bF[n], aF[m], acc[m][n], 0, 0, 0);
    __builtin_amdgcn_s_setprio(0);
    if (t + 1 < nt) STG4(0, t + 1);            // A(t+1) -> buf^1
    // ---- kk1
#pragma unroll
    for (int n = 0; n < 4; ++n) bF[n] = *(const bf16x8*)(base + bBase + n * 2048 + k1b);
#pragma unroll
    for (int m = 0; m < 8; ++m) aF[m] = *(const bf16x8*)(base + aBase + m * 2048 + k1b);
    __builtin_amdgcn_s_setprio(1);
#pragma unroll
    for (int m = 0; m < 8; ++m)
#pragma unroll
      for (int n = 0; n < 4; ++n)
        acc[m][n] = MFMA16(bF[n], aF[m], acc[m][n], 0, 0, 0);
    __builtin_amdgcn_s_setprio(0);
    // ---- tile end: all my reads from buf done; my stages landed; sync
    asm volatile("s_waitcnt lgkmcnt(0)" ::: "memory");
    asm volatile("s_waitcnt vmcnt(0)" ::: "memory");
    __builtin_amdgcn_s_barrier();
  }
#undef STG4

  ushort_t* Cbz = Cb + (long long)blockIdx.z * pstr;
#pragma unroll
  for (int n = 0; n < 4; ++n) {
    int colb = n0 + wn * 64 + n * 16 + lk * 4;    // 4 consecutive cols
    int seg = colb >> 10;
    const float* bp = seg == 0 ? b0 : seg == 1 ? b1 : seg == 2 ? b2 : b3;
    float4 bv = *(const float4*)(bp + (colb & 1023));
    if (blockIdx.z != 0) { bv.x = bv.y = bv.z = bv.w = 0.f; }
#pragma unroll
    for (int m = 0; m < 8; ++m) {
      int row = m0 + wm * 128 + m * 16 + lrow;
      float v0 = acc[m][n][0] + bv.x, v1 = acc[m][n][1] + bv.y;
      float v2 = acc[m][n][2] + bv.z, v3 = acc[m][n][3] + bv.w;
      if (RELU) {
        v0 = fmaxf(v0, 0.f); v1 = fmaxf(v1, 0.f);
        v2 = fmaxf(v2, 0.f); v3 = fmaxf(v3, 0.f);
      }
      *(uint2*)&Cbz[(size_t)row * N + colb] = pk4(v0, v1, v2, v3);
    }
  }
}

// ---------------------------------------------------------------- attention
// SPLIT-KV=2 (flash-decoding): grid (bh=64, yb=8, hz=2). Half hz handles
// K-tiles [tLo,tHi) -> longest serial chain 16 -> 8 tiles; 40KB LDS +
// bounds(256,4) so 4 halved chains co-reside per CU. Each half writes
// UNNORMALIZED O (bf16) + per-row (m,l); combine kernel merges exactly.
// Core = R13 per-tile body (swapped QK^T/PV, T13 defer-max, sP reuse).
template <int CAUSAL>
__global__ __launch_bounds__(256, 4) void attn_kernel(
    const ushort_t* __restrict__ Q, int ldq,
    const ushort_t* __restrict__ Kp, int ldk,
    const ushort_t* __restrict__ vT,  // [B*H,64,1024]
    const float* __restrict__ mask2,  // [B,1024] or null
    ushort_t* __restrict__ op,        // [2][64*1024*64] bf16 unnormalized O
    float2* __restrict__ ml) {        // [2][64*1024] (m, l)
  __shared__ ushort_t sK[2][4096];    // [64 key][64 dh] swizzled, 8KB each
  __shared__ ushort_t sV[2][4096];    // [64 dh][64 key] swizzled
  __shared__ ushort_t sP[4][1024];    // per-wave [16 q][64 key], reused per g
  const int bh = blockIdx.x;
  const int yb = blockIdx.y;                    // 0..7
  const int qb = (yb < 4) ? yb : 11 - yb;       // complementary pairing
  const int hz = blockIdx.z;                    // KV half
  const int b = bh >> 4, h = bh & 15;
  const int tid = threadIdx.x, w = tid >> 6, lane = tid & 63;
  const int lrow = lane & 15, lk = lane >> 4;
  const int q0 = qb * 128 + w * 32;   // wave's first q row (within seq)

  bf16x8 qF[2][2];
#pragma unroll
  for (int g = 0; g < 2; ++g) {
    const ushort_t* qptr =
        Q + (size_t)(b * 1024 + q0 + g * 16 + lrow) * ldq + h * 64 + lk * 8;
    qF[g][0] = *(const bf16x8*)qptr;
    qF[g][1] = *(const bf16x8*)(qptr + 32);
  }
  f32x4 oacc[2][4] = {};              // [g][t][j]: q=g*16+lrow, d=t*16+lk*4+j
  float m_[2] = {-3.0e38f, -3.0e38f}, l_[2] = {0.f, 0.f};  // per-lane q=lrow
  const int ntile = CAUSAL ? (qb * 2 + 2) : 16;
  const int half0 = (ntile + 1) >> 1;           // tiles in half 0
  const int tLo = hz ? half0 : 0;
  const int tHi = hz ? ntile : half0;
  const float C = 0.18033688011112042f;  // 0.125 * log2(e)

  const int sr = w * 16 + (lane >> 3);                  // staging row in 64
  const int scb = (((lane & 7) ^ (lane >> 3)) * 16);    // swizzled col byte
  const ushort_t* kbase = Kp + (size_t)(b * 1024 + sr) * ldk + h * 64 + (scb >> 1);
  const ushort_t* vbase = vT + ((size_t)bh * 64 + sr) * 1024 + (scb >> 1);
  char* dstK0 = (char*)sK[0] + w * 2048;  // HW adds lane*16
  char* dstV0 = (char*)sV[0] + w * 2048;

#define STAGE(kb_, bufi)                                              \
  do {                                                                \
    const ushort_t* gk = kbase + (size_t)(kb_) * 64 * ldk;            \
    gload16(gk, dstK0 + (bufi) * 8192);                               \
    gload16(gk + (size_t)8 * ldk, dstK0 + (bufi) * 8192 + 1024);      \
    const ushort_t* gv = vbase + (kb_) * 64;                          \
    gload16(gv, dstV0 + (bufi) * 8192);                               \
    gload16(gv + (size_t)8 * 1024, dstV0 + (bufi) * 8192 + 1024);     \
  } while (0)

  STAGE(tLo, 0);
  const int swz = (lrow & 7) << 4;

  for (int kb = tLo; kb < tHi; ++kb) {
    const int buf = (kb - tLo) & 1;
    __syncthreads();                       // drains vmcnt: buf ready, buf^1 free
    if (kb + 1 < tHi) STAGE(kb + 1, buf ^ 1);

    const char* kB = (const char*)sK[buf];
    const char* vB = (const char*)sV[buf];
    // per-group causal tile classification (wave-uniform)
    bool skip[2], edge[2];
#pragma unroll
    for (int g = 0; g < 2; ++g) {
      int qming = q0 + g * 16;
      skip[g] = CAUSAL && (kb * 64 > qming + 15);
      edge[g] = CAUSAL && !skip[g] && (kb * 64 + 63 > qming);
    }
    if (CAUSAL && skip[0] && skip[1]) continue;
    // ---- QK^T swapped, K fragments shared across both q-groups
    f32x4 sc[2][4];
    __builtin_amdgcn_s_setprio(1);
#pragma unroll
    for (int kt = 0; kt < 4; ++kt) {
      const char* rp = kB + ((kt * 16 + lrow) << 7);
      bf16x8 k0 = *(const bf16x8*)(rp + ((lk * 16) ^ swz));
      bf16x8 k1 = *(const bf16x8*)(rp + ((64 + lk * 16) ^ swz));
      f32x4 z0 = {};
      z0 = MFMA16(k0, qF[0][0], z0, 0, 0, 0);
      sc[0][kt] = MFMA16(k1, qF[0][1], z0, 0, 0, 0);
      f32x4 z1 = {};
      z1 = MFMA16(k0, qF[1][0], z1, 0, 0, 0);
      sc[1][kt] = MFMA16(k1, qF[1][1], z1, 0, 0, 0);
    }
    __builtin_amdgcn_s_setprio(0);
    // ---- mask values (shared across groups: depend on key only)
    float4 mv[4];
    if (!CAUSAL) {
#pragma unroll
      for (int kt = 0; kt < 4; ++kt)
        mv[kt] = *(const float4*)&mask2[b * 1024 + kb * 64 + kt * 16 + lk * 4];
    }
    // ---- per-group softmax + P pack + immediate pF read (buffer reuse)
    bf16x8 pF[2][2];
#pragma unroll
    for (int g = 0; g < 2; ++g) {
      if (skip[g]) continue;
      if (CAUSAL) {
        if (edge[g]) {
          int qrel = q0 + g * 16 + lrow - kb * 64;
#pragma unroll
          for (int kt = 0; kt < 4; ++kt)
#pragma unroll
            for (int j = 0; j < 4; ++j)
              if (kt * 16 + lk * 4 + j > qrel) sc[g][kt][j] = -3.0e38f;
        }
      } else {
#pragma unroll
        for (int kt = 0; kt < 4; ++kt) {
          sc[g][kt][0] = fmaf(mv[kt].x, -8e9f, sc[g][kt][0]);
          sc[g][kt][1] = fmaf(mv[kt].y, -8e9f, sc[g][kt][1]);
          sc[g][kt][2] = fmaf(mv[kt].z, -8e9f, sc[g][kt][2]);
          sc[g][kt][3] = fmaf(mv[kt].w, -8e9f, sc[g][kt][3]);
        }
      }
      // max tree: nested triples -> v_max3, parallel sub-chains
      float a0 = fmaxf(fmaxf(sc[g][0][0], sc[g][0][1]), sc[g][0][2]);
      float a1 = fmaxf(fmaxf(sc[g][0][3], sc[g][1][0]), sc[g][1][1]);
      float a2 = fmaxf(fmaxf(sc[g][1][2], sc[g][1][3]), sc[g][2][0]);
      float a3 = fmaxf(fmaxf(sc[g][2][1], sc[g][2][2]), sc[g][2][3]);
      float a4 = fmaxf(fmaxf(sc[g][3][0], sc[g][3][1]), sc[g][3][2]);
      float pmax = fmaxf(fmaxf(fmaxf(a0, a1), fmaxf(a2, a3)),
                         fmaxf(a4, sc[g][3][3]));
      pmax = fmaxf(pmax, __shfl_xor(pmax, 16));
      pmax = fmaxf(pmax, __shfl_xor(pmax, 32));
      if (__any(pmax - m_[g] > 64.f)) {    // T13 defer-max; scale lane-local
        float mnew = fmaxf(m_[g], pmax);
        float scale = __builtin_exp2f((m_[g] - mnew) * C);
        l_[g] *= scale;
        m_[g] = mnew;
#pragma unroll
        for (int t = 0; t < 4; ++t) {
          oacc[g][t][0] *= scale; oacc[g][t][1] *= scale;
          oacc[g][t][2] *= scale; oacc[g][t][3] *= scale;
        }
      }
      const float mC = m_[g] * C;
      float psk[4] = {0.f, 0.f, 0.f, 0.f};   // 4 parallel accumulators
#pragma unroll
      for (int kt = 0; kt < 4; ++kt)
#pragma unroll
        for (int j = 0; j < 4; ++j) {
          float e = __builtin_exp2f(fmaf(sc[g][kt][j], C, -mC));
          sc[g][kt][j] = e;
          psk[kt] += e;
        }
      float ps = (psk[0] + psk[1]) + (psk[2] + psk[3]);
      ps += __shfl_xor(ps, 16);
      ps += __shfl_xor(ps, 32);
      l_[g] += ps;
      char* bp = (char*)sP[w] + lrow * 128;   // 16-row buffer reused per g
#pragma unroll
      for (int kt = 0; kt < 4; ++kt) {
        uint2 dd = pk4(sc[g][kt][0], sc[g][kt][1], sc[g][kt][2], sc[g][kt][3]);
        *(uint2*)(bp + ((kt * 32 + lk * 8) ^ swz)) = dd;
      }
      // immediate readback (wave-local in-order DS): values land in regs
      pF[g][0] = *(const bf16x8*)(bp + ((lk * 16) ^ swz));
      pF[g][1] = *(const bf16x8*)(bp + ((64 + lk * 16) ^ swz));
    }
    // ---- PV swapped: oacc = mfma(vF, pF) -> d cols lane-local
    __builtin_amdgcn_s_setprio(1);
#pragma unroll
    for (int t = 0; t < 4; ++t) {
      const char* rp = vB + ((t * 16 + lrow) << 7);
      bf16x8 v0 = *(const bf16x8*)(rp + ((lk * 16) ^ swz));
      bf16x8 v1 = *(const bf16x8*)(rp + ((64 + lk * 16) ^ swz));
      if (!skip[0]) {
        oacc[0][t] = MFMA16(v0, pF[0][0], oacc[0][t], 0, 0, 0);
        oacc[0][t] = MFMA16(v1, pF[0][1], oacc[0][t], 0, 0, 0);
      }
      if (!skip[1]) {
        oacc[1][t] = MFMA16(v0, pF[1][0], oacc[1][t], 0, 0, 0);
        oacc[1][t] = MFMA16(v1, pF[1][1], oacc[1][t], 0, 0, 0);
      }
    }
    __builtin_amdgcn_s_setprio(0);
  }
#undef STAGE
  // ---- epilogue: write unnormalized O partial + (m,l) per q row
#pragma unroll
  for (int g = 0; g < 2; ++g) {
    int row = q0 + g * 16 + lrow;
    size_t rbase = (size_t)bh * 1024 + row;
    if (lk == 0) {
      float2 v; v.x = m_[g]; v.y = l_[g];
      ml[(size_t)hz * 65536 + rbase] = v;
    }
    ushort_t* opp = op + (size_t)hz * 4194304 + rbase * 64;
#pragma unroll
    for (int t = 0; t < 4; ++t) {
      uint2 dd = pk4(oacc[g][t][0], oacc[g][t][1], oacc[g][t][2], oacc[g][t][3]);
      *(uint2*)&opp[t * 16 + lk * 4] = dd;
    }
  }
}

// combine: O = (e0*O0 + e1*O1) / (e0*l0 + e1*l1), e_h = exp2((m_h - m)*C)
__global__ __launch_bounds__(256) void attn_combine_kernel(
    const ushort_t* __restrict__ op, const float2* __restrict__ ml,
    ushort_t* __restrict__ O) {
  const int r = blockIdx.x;             // 0..4095 = b*1024 + row
  const int b = r >> 10, row = r & 1023;
  const int tid = threadIdx.x;
  __shared__ float s0s[16], s1s[16], ivs[16];
  if (tid < 16) {
    size_t rb = (size_t)(b * 16 + tid) * 1024 + row;
    float2 a = ml[rb];
    float2 c = ml[65536 + rb];
    float m = fmaxf(a.x, c.x);
    float e0 = __builtin_exp2f((a.x - m) * 0.18033688011112042f);
    float e1 = __builtin_exp2f((c.x - m) * 0.18033688011112042f);
    s0s[tid] = e0; s1s[tid] = e1;
    ivs[tid] = 1.f / (e0 * a.y + e1 * c.y);
  }
  __syncthreads();
  const int h = tid >> 4, d = (tid & 15) * 4;
  size_t base = ((size_t)(b * 16 + h) * 1024 + row) * 64 + d;
  us4 a4 = *(const us4*)&op[base];
  us4 b4 = *(const us4*)&op[4194304 + base];
  float s0 = s0s[h], s1 = s1s[h], iv = ivs[h];
  float o0 = (bf2f(a4.x) * s0 + bf2f(b4.x) * s1) * iv;
  float o1 = (bf2f(a4.y) * s0 + bf2f(b4.y) * s1) * iv;
  float o2 = (bf2f(a4.z) * s0 + bf2f(b4.z) * s1) * iv;
  float o3 = (bf2f(a4.w) * s0 + bf2f(b4.w) * s1) * iv;
  *(uint2*)&O[(size_t)r * 1024 + h * 64 + d] = pk4(o0, o1, o2, o3);
}

// ---------------------------------------------------------------- layernorm
// y = LN(sum(bf16 partials) + residual) * g + beta
// RESBF: residual bf16 (else f32). WF32: write f32 (LN3) else bf16.
template <int RESBF, int NPART, int WF32>
__global__ __launch_bounds__(256) void ln_kernel(
    const ushort_t* __restrict__ p0, const ushort_t* __restrict__ p1,
    const ushort_t* __restrict__ p2, const ushort_t* __restrict__ p3,
    const void* __restrict__ rp,
    const float* __restrict__ g, const float* __restrict__ be,
    float* __restrict__ yf, ushort_t* __restrict__ yb) {
  int row = blockIdx.x, tid = threadIdx.x;
  size_t off = (size_t)row * 1024 + tid * 4;
  us4 a = *(const us4*)(p0 + off);
  float x0 = bf2f(a.x), x1 = bf2f(a.y), x2 = bf2f(a.z), x3 = bf2f(a.w);
  if (NPART >= 2) {
    us4 t = *(const us4*)(p1 + off);
    x0 += bf2f(t.x); x1 += bf2f(t.y); x2 += bf2f(t.z); x3 += bf2f(t.w);
  }
  if (NPART >= 4) {
    us4 t2 = *(const us4*)(p2 + off);
    us4 t3 = *(const us4*)(p3 + off);
    x0 += bf2f(t2.x) + bf2f(t3.x); x1 += bf2f(t2.y) + bf2f(t3.y);
    x2 += bf2f(t2.z) + bf2f(t3.z); x3 += bf2f(t2.w) + bf2f(t3.w);
  }
  if (RESBF) {
    us4 r = *(const us4*)((const ushort_t*)rp + off);
    x0 += bf2f(r.x); x1 += bf2f(r.y); x2 += bf2f(r.z); x3 += bf2f(r.w);
  } else {
    float4 r = *(const float4*)((const float*)rp + off);
    x0 += r.x; x1 += r.y; x2 += r.z; x3 += r.w;
  }
  float s = x0 + x1 + x2 + x3;
  float s2 = x0 * x0 + x1 * x1 + x2 * x2 + x3 * x3;
#pragma unroll
  for (int o = 1; o < 64; o <<= 1) { s += __shfl_xor(s, o); s2 += __shfl_xor(s2, o); }
  __shared__ float sh[8];
  if ((tid & 63) == 0) { sh[tid >> 6] = s; sh[4 + (tid >> 6)] = s2; }
  __syncthreads();
  s = sh[0] + sh[1] + sh[2] + sh[3];
  s2 = sh[4] + sh[5] + sh[6] + sh[7];
  float mu = s * 0.0009765625f;
  float var = s2 * 0.0009765625f - mu * mu;
  float inv = rsqrtf(var + 1e-6f);
  float4 gv = *(const float4*)(g + tid * 4);
  float4 bv = *(const float4*)(be + tid * 4);
  float y0 = (x0 - mu) * inv * gv.x + bv.x;
  float y1 = (x1 - mu) * inv * gv.y + bv.y;
  float y2 = (x2 - mu) * inv * gv.z + bv.z;
  float y3 = (x3 - mu) * inv * gv.w + bv.w;
  if (WF32) {
    *(float4*)(yf + off) = make_float4(y0, y1, y2, y3);
  } else {
    us4 o; o.x = f2bf(y0); o.y = f2bf(y1); o.z = f2bf(y2); o.w = f2bf(y3);
    *(us4*)(yb + off) = o;
  }
}

// ---------------------------------------------------------------- launcher
extern "C" void kernel_launch(void* const* d_in, const int* in_sizes, int n_in,
                              void* d_out, int out_size, void* d_ws, size_t ws_size,
                              hipStream_t stream) {
  (void)in_sizes; (void)n_in; (void)out_size; (void)ws_size;
  const float* inputs = (const float*)d_in[0];
  const float* enc    = (const float*)d_in[1];
  const float* mask2  = (const float*)d_in[3];
  const float* wq1 = (const float*)d_in[4];  const float* bq1 = (const float*)d_in[5];
  const float* wk1 = (const float*)d_in[6];  const float* bk1 = (const float*)d_in[7];
  const float* wv1 = (const float*)d_in[8];  const float* bv1 = (const float*)d_in[9];
  const float* wo1 = (const float*)d_in[10]; const float* bo1 = (const float*)d_in[11];
  const float* wq2 = (const float*)d_in[12]; const float* bq2 = (const float*)d_in[13];
  const float* wk2 = (const float*)d_in[14]; const float* bk2 = (const float*)d_in[15];
  const float* wv2 = (const float*)d_in[16]; const float* bv2 = (const float*)d_in[17];
  const float* wo2 = (const float*)d_in[18]; const float* bo2 = (const float*)d_in[19];
  const float* wff1 = (const float*)d_in[20]; const float* bff1 = (const float*)d_in[21];
  const float* wff2 = (const float*)d_in[22]; const float* bff2 = (const float*)d_in[23];
  const float* g1 = (const float*)d_in[24]; const float* be1 = (const float*)d_in[25];
  const float* g2 = (const float*)d_in[26]; const float* be2 = (const float*)d_in[27];
  const float* g3 = (const float*)d_in[28]; const float* be3 = (const float*)d_in[29];

  char* ws = (char*)d_ws;
  const size_t MB = 1024 * 1024;
  const size_t W1M = 1048576;  // elements per 1024x1024 weight
  // --- workspace map (liveness verified per stream order) ---
  ushort_t* wt    = (ushort_t*)ws;              // 0..32MB  bf16 W^T
  ushort_t* xb    = (ushort_t*)(ws + 32 * MB);  // 32..40   input bf16 (dead after QKV)
  ushort_t* encb  = (ushort_t*)(ws + 40 * MB);  // 40..48   enc bf16 (dead after KV2)
  ushort_t* qkvb  = (ushort_t*)(ws + 48 * MB);  // 48..72   QKV (dead after attn1)
  ushort_t* vtb   = (ushort_t*)(ws + 72 * MB);  // 72..80   vT (per attention)
  ushort_t* attnb = (ushort_t*)(ws + 80 * MB);  // 80..88   attn out bf16
  ushort_t* y1b   = (ushort_t*)(ws + 88 * MB);  // 88..96   LN1 out (Q2 A + LN2 residual)
  ushort_t* y2b   = (ushort_t*)(ws + 96 * MB);  // 96..104  LN2 out (FFN1 A + LN3 residual)
  ushort_t* cp    = (ushort_t*)(ws + 104 * MB); // 104..120 split-K bf16 partials (2x8MB)
  ushort_t* opart = (ushort_t*)(ws + 104 * MB); // 104..120 attn O partials (2x8MB, pre-gemm)
  float2*   mlb   = (float2*)(ws + 136 * MB);   // 136..137 attn (m,l) partials
  ushort_t* q2b   = (ushort_t*)(ws + 32 * MB);  // 32..40   Q2 bf16 (over dead xb)
  ushort_t* kv2b  = (ushort_t*)(ws + 56 * MB);  // 56..72   KV2 (dead after attn2)
  ushort_t* hb    = (ushort_t*)(ws + 32 * MB);  // 32..64   FFN hidden (after attn2)
  ushort_t* pp    = (ushort_t*)(ws + 104 * MB); // 104..136 FF2 partials 4x8MB
  float* outf = (float*)d_out;
  const long long PE = 4LL * 1024 * 1024;  // elements per 8MB bf16 partial

  // prep: fused casts + weight transposes
  cast2_bf16_kernel<<<8192, 256, 0, stream>>>(inputs, xb, enc, encb);
  Src8 s8; s8.p[0] = wq1; s8.p[1] = wk1; s8.p[2] = wv1; s8.p[3] = wo1;
           s8.p[4] = wq2; s8.p[5] = wk2; s8.p[6] = wv2; s8.p[7] = wo2;
  transpose_cast8_kernel<<<dim3(16, 16, 8), 256, 0, stream>>>(s8, wt);
  transpose_cast_kernel<<<dim3(64, 16), 256, 0, stream>>>(wff1, wt + 8 * W1M, 1024, 4096);
  transpose_cast_kernel<<<dim3(16, 64), 256, 0, stream>>>(wff2, wt + 12 * W1M, 4096, 1024);

  // ---- self-attention
  gemm256<0><<<dim3(16, 12, 1), 512, 131072, stream>>>(
      xb, wt, bq1, bk1, bv1, bv1, qkvb, 4096, 3072, 1024, 1024, 0);
  transpose_v_kernel<<<dim3(16, 64), 256, 0, stream>>>(qkvb + 2048, 3072, vtb);
  attn_kernel<1><<<dim3(64, 8, 2), 256, 0, stream>>>(
      qkvb, 3072, qkvb + 1024, 3072, vtb, nullptr, opart, mlb);
  attn_combine_kernel<<<4096, 256, 0, stream>>>(opart, mlb, attnb);
  gemm_bt<0><<<dim3(32, 8, 2), 256, 0, stream>>>(                // split-K=2
      attnb, wt + 3 * W1M, bo1, bo1, bo1, bo1, cp, 4096, 1024, 1024, 512, PE);
  ln_kernel<0, 2, 0><<<4096, 256, 0, stream>>>(cp, cp + PE, nullptr, nullptr,
                                               inputs, g1, be1, nullptr, y1b);

  // ---- cross-attention
  gemm_bt<0><<<dim3(32, 8, 2), 256, 0, stream>>>(                // Q2 split-K=2
      y1b, wt + 4 * W1M, bq2, bq2, bq2, bq2, cp, 4096, 1024, 1024, 512, PE);
  reduce_cast_kernel<<<4096, 256, 0, stream>>>(cp, cp + PE, q2b, 1048576);
  gemm_bt<0><<<dim3(32, 16, 1), 256, 0, stream>>>(
      encb, wt + 5 * W1M, bk2, bv2, bk2, bk2, kv2b, 4096, 2048, 1024, 1024, 0);
  transpose_v_kernel<<<dim3(16, 64), 256, 0, stream>>>(kv2b + 1024, 2048, vtb);
  attn_kernel<0><<<dim3(64, 8, 2), 256, 0, stream>>>(
      q2b, 1024, kv2b, 2048, vtb, mask2, opart, mlb);
  attn_combine_kernel<<<4096, 256, 0, stream>>>(opart, mlb, attnb);
  gemm_bt<0><<<dim3(32, 8, 2), 256, 0, stream>>>(                // split-K=2
      attnb, wt + 7 * W1M, bo2, bo2, bo2, bo2, cp, 4096, 1024, 1024, 512, PE);
  ln_kernel<1, 2, 0><<<4096, 256, 0, stream>>>(cp, cp + PE, nullptr, nullptr,
                                               y1b, g2, be2, nullptr, y2b);

  // ---- FFN
  gemm256<1><<<dim3(16, 16, 1), 512, 131072, stream>>>(
      y2b, wt + 8 * W1M, bff1, bff1 + 1024, bff1 + 2048, bff1 + 3072,
      hb, 4096, 4096, 1024, 1024, 0);
  gemm256<0><<<dim3(16, 4, 4), 512, 131072, stream>>>(           // FF2 split-K=4
      hb, wt + 12 * W1M, bff2, bff2, bff2, bff2, pp, 4096, 1024, 4096, 1024, PE);
  ln_kernel<1, 4, 1><<<4096, 256, 0, stream>>>(pp, pp + PE, pp + 2 * PE, pp + 3 * PE,
                                               y2b, g3, be3, outf, nullptr);
}

// Round 19
// 345.317 us; speedup vs baseline: 1.0440x; 1.0440x over previous
//
#include <hip/hip_runtime.h>
#include <stdint.h>

typedef unsigned short ushort_t;
typedef __attribute__((ext_vector_type(8))) short bf16x8;   // 8 bf16 in 4 VGPRs
typedef __attribute__((ext_vector_type(4))) float f32x4;
typedef __attribute__((ext_vector_type(4))) unsigned short us4;

#define DEV __device__ __forceinline__

DEV unsigned short f2bf(float f) {           // RNE f32 -> bf16
  union { float f; unsigned u; } x; x.f = f;
  unsigned r = x.u + 0x7fffu + ((x.u >> 16) & 1u);
  return (unsigned short)(r >> 16);
}

DEV float bf2f(unsigned short u) {
  union { unsigned u; float f; } x; x.u = (unsigned)u << 16; return x.f;
}

DEV uint2 pk4(float v0, float v1, float v2, float v3) {  // 4 f32 -> 4 bf16 (RNE)
  unsigned d0, d1;
  asm("v_cvt_pk_bf16_f32 %0, %1, %2" : "=v"(d0) : "v"(v0), "v"(v1));
  asm("v_cvt_pk_bf16_f32 %0, %1, %2" : "=v"(d1) : "v"(v2), "v"(v3));
  uint2 r; r.x = d0; r.y = d1; return r;
}

DEV void gload16(const void* g, void* l) {   // async global->LDS, 16B/lane
  __builtin_amdgcn_global_load_lds(
      (const __attribute__((address_space(1))) unsigned int*)g,
      (__attribute__((address_space(3))) unsigned int*)l, 16, 0, 0);
}

#define MFMA16 __builtin_amdgcn_mfma_f32_16x16x32_bf16

// ---------------------------------------------------------------- casts
// fused: blocks [0,4096) cast x0->y0, [4096,8192) cast x1->y1
__global__ __launch_bounds__(256) void cast2_bf16_kernel(
    const float* __restrict__ x0, ushort_t* __restrict__ y0,
    const float* __restrict__ x1, ushort_t* __restrict__ y1) {
  int blk = blockIdx.x;
  const float* x = (blk < 4096) ? x0 : x1;
  ushort_t* y = (blk < 4096) ? y0 : y1;
  int i = (blk & 4095) * 256 + threadIdx.x;
  float4 v = ((const float4*)x)[i];
  us4 o; o.x = f2bf(v.x); o.y = f2bf(v.y); o.z = f2bf(v.z); o.w = f2bf(v.w);
  ((us4*)y)[i] = o;
}

// y[i] = bf16(p0[i] + p1[i])  (bf16 split-K partials)
__global__ __launch_bounds__(256) void reduce_cast_kernel(
    const ushort_t* __restrict__ p0, const ushort_t* __restrict__ p1,
    ushort_t* __restrict__ y, int n4) {
  int i = blockIdx.x * 256 + threadIdx.x;
  if (i >= n4) return;
  us4 a = ((const us4*)p0)[i];
  us4 b = ((const us4*)p1)[i];
  us4 o;
  o.x = f2bf(bf2f(a.x) + bf2f(b.x));
  o.y = f2bf(bf2f(a.y) + bf2f(b.y));
  o.z = f2bf(bf2f(a.z) + bf2f(b.z));
  o.w = f2bf(bf2f(a.w) + bf2f(b.w));
  ((us4*)y)[i] = o;
}

// W[K,N] f32 -> Wt[N,K] bf16 (generic dims)
__global__ __launch_bounds__(256) void transpose_cast_kernel(
    const float* __restrict__ W, ushort_t* __restrict__ dst, int K, int N) {
  __shared__ float tile[64][65];
  int n0 = blockIdx.x * 64, k0 = blockIdx.y * 64;
  int tid = threadIdx.x;
#pragma unroll
  for (int it = 0; it < 16; ++it) {
    int idx = it * 256 + tid; int r = idx >> 6, c = idx & 63;
    tile[r][c] = W[(size_t)(k0 + r) * N + n0 + c];
  }
  __syncthreads();
#pragma unroll
  for (int it = 0; it < 16; ++it) {
    int idx = it * 256 + tid; int r = idx >> 6, c = idx & 63;
    dst[(size_t)(n0 + r) * K + k0 + c] = f2bf(tile[c][r]);
  }
}

struct Src8 { const float* p[8]; };
// 8x fused 1024x1024 weight transposes (one launch)
__global__ __launch_bounds__(256) void transpose_cast8_kernel(
    Src8 s, ushort_t* __restrict__ dst) {
  __shared__ float tile[64][65];
  const float* W = s.p[blockIdx.z];
  ushort_t* out = dst + (size_t)blockIdx.z * 1048576;
  int n0 = blockIdx.x * 64, k0 = blockIdx.y * 64;
  int tid = threadIdx.x;
#pragma unroll
  for (int it = 0; it < 16; ++it) {
    int idx = it * 256 + tid; int r = idx >> 6, c = idx & 63;
    tile[r][c] = W[(size_t)(k0 + r) * 1024 + n0 + c];
  }
  __syncthreads();
#pragma unroll
  for (int it = 0; it < 16; ++it) {
    int idx = it * 256 + tid; int r = idx >> 6, c = idx & 63;
    out[(size_t)(n0 + r) * 1024 + k0 + c] = f2bf(tile[c][r]);
  }
}

// V [B,S,(ldv)] head-cols -> vT [B*H, 64, 1024]   (us4-vectorized global I/O)
__global__ __launch_bounds__(256) void transpose_v_kernel(
    const ushort_t* __restrict__ V, int ldv, ushort_t* __restrict__ vT) {
  __shared__ ushort_t tile[64][65];
  int s0 = blockIdx.x * 64;
  int bh = blockIdx.y;
  int b = bh >> 4, h = bh & 15;
  int tid = threadIdx.x;
#pragma unroll
  for (int it = 0; it < 4; ++it) {
    int idx = it * 256 + tid; int r = idx >> 4, c = (idx & 15) * 4;
    us4 v = *(const us4*)&V[(size_t)(b * 1024 + s0 + r) * ldv + h * 64 + c];
    tile[r][c] = v.x; tile[r][c + 1] = v.y; tile[r][c + 2] = v.z; tile[r][c + 3] = v.w;
  }
  __syncthreads();
#pragma unroll
  for (int it = 0; it < 4; ++it) {
    int idx = it * 256 + tid; int r = idx >> 4, c = (idx & 15) * 4;
    us4 o; o.x = tile[c][r]; o.y = tile[c + 1][r]; o.z = tile[c + 2][r]; o.w = tile[c + 3][r];
    *(us4*)&vT[((size_t)bh * 64 + r) * 1024 + s0 + c] = o;
  }
}

// ---------------------------------------------------------------- GEMM 128^2
// OPERAND-SWAPPED MFMA: acc[m][n] = mfma(bF_n, aF_m) => lane holds 4
// CONSECUTIVE output cols (reg j) of row ..+lrow -> 8B dwordx2 C-stores.
template <int RELU>
__global__ __launch_bounds__(256, 2) void gemm_bt(
    const ushort_t* __restrict__ A, const ushort_t* __restrict__ Bt,
    const float* __restrict__ b0, const float* __restrict__ b1,
    const float* __restrict__ b2, const float* __restrict__ b3,
    ushort_t* __restrict__ Cb, int M, int N, int K, int Ks, long long pstr) {
  __shared__ ushort_t sA[4096];  // [128][32] bf16, 8KB
  __shared__ ushort_t sB[4096];
  const int tid = threadIdx.x;
  const int w = tid >> 6, lane = tid & 63;
  const int lrow = lane & 15, lk = lane >> 4;
  const int m0 = blockIdx.x * 128, n0 = blockIdx.y * 128;
  const int kz = blockIdx.z * Ks;
  const int wr = w >> 1, wc = w & 1;
  f32x4 acc[4][4] = {};
  const int brow0 = (w * 1024 + lane * 16) >> 6;  // row for sweep 0
  const int kbyte = (lane * 16) & 63;             // byte within 64B row

  for (int kt = kz; kt < kz + Ks; kt += 32) {
    __syncthreads();
    const ushort_t* ga = A + (size_t)(m0 + brow0) * K + kt + (kbyte >> 1);
    gload16(ga, (char*)sA + w * 1024);
    gload16(ga + (size_t)64 * K, (char*)sA + 4096 + w * 1024);
    const ushort_t* gb = Bt + (size_t)(n0 + brow0) * K + kt + (kbyte >> 1);
    gload16(gb, (char*)sB + w * 1024);
    gload16(gb + (size_t)64 * K, (char*)sB + 4096 + w * 1024);
    __syncthreads();
    bf16x8 aF[4], bF[4];
#pragma unroll
    for (int t = 0; t < 4; ++t) {
      bF[t] = *(const bf16x8*)((const char*)sB + ((wc * 64 + t * 16 + lrow) << 6) + (lk << 4));
      aF[t] = *(const bf16x8*)((const char*)sA + ((wr * 64 + t * 16 + lrow) << 6) + (lk << 4));
    }
#pragma unroll
    for (int mt = 0; mt < 4; ++mt)
#pragma unroll
      for (int nt = 0; nt < 4; ++nt)
        acc[mt][nt] = MFMA16(bF[nt], aF[mt], acc[mt][nt], 0, 0, 0);
  }
  ushort_t* Cbz = Cb + (long long)blockIdx.z * pstr;
#pragma unroll
  for (int nt = 0; nt < 4; ++nt) {
    int colb = n0 + wc * 64 + nt * 16 + lk * 4;   // 4 consecutive cols
    int seg = colb >> 10;
    const float* bp = seg == 0 ? b0 : seg == 1 ? b1 : seg == 2 ? b2 : b3;
    float4 bv = *(const float4*)(bp + (colb & 1023));
    if (blockIdx.z != 0) { bv.x = bv.y = bv.z = bv.w = 0.f; }
#pragma unroll
    for (int mt = 0; mt < 4; ++mt) {
      int row = m0 + wr * 64 + mt * 16 + lrow;
      float v0 = acc[mt][nt][0] + bv.x, v1 = acc[mt][nt][1] + bv.y;
      float v2 = acc[mt][nt][2] + bv.z, v3 = acc[mt][nt][3] + bv.w;
      if (RELU) {
        v0 = fmaxf(v0, 0.f); v1 = fmaxf(v1, 0.f);
        v2 = fmaxf(v2, 0.f); v3 = fmaxf(v3, 0.f);
      }
      *(uint2*)&Cbz[(size_t)row * N + colb] = pk4(v0, v1, v2, v3);
    }
  }
}

// ---------------------------------------------------------------- GEMM 256^2
// SINGLE-BARRIER-PER-TILE (R12-verified). Swizzle byte ^= (row&7)<<4 both
// sides (0 conflicts). Operand-swapped MFMA => vectorized 8B C-stores.
template <int RELU>
__global__ __launch_bounds__(512, 1) void gemm256(
    const ushort_t* __restrict__ A, const ushort_t* __restrict__ Bt,
    const float* __restrict__ b0, const float* __restrict__ b1,
    const float* __restrict__ b2, const float* __restrict__ b3,
    ushort_t* __restrict__ Cb, int M, int N, int K, int Ks, long long pstr) {
  extern __shared__ char L[];  // 131072 bytes
  const int tid = threadIdx.x;
  const int w = tid >> 6, lane = tid & 63;
  const int lrow = lane & 15, lk = lane >> 4;
  const int wm = w >> 2, wn = w & 3;
  const int m0 = blockIdx.x * 256, n0 = blockIdx.y * 256;
  const int kz = blockIdx.z * Ks;
  const int nt = Ks >> 6;

  const int srow = w * 8 + (lane >> 3);
  const int gsw = (lane & 7) ^ ((lane >> 3) & 7);
  const ushort_t* srcA = A + (size_t)(m0 + srow) * K + kz + gsw * 8;
  const ushort_t* srcB = Bt + (size_t)(n0 + srow) * K + kz + gsw * 8;
  const int dstw = w * 1024;

  // stage whole matrix M_ (0=A,1=B) of tile T_ (4 gloads, sweeps 0..3)
#define STG4(M_, T_)                                                  \
  do {                                                                \
    const ushort_t* g0 = ((M_) ? srcB : srcA) + (size_t)(T_) * 64;    \
    char* d_ = L + (((T_) & 1) << 16) + ((M_) << 15) + dstw;          \
    gload16(g0, d_);                                                  \
    gload16(g0 + (size_t)64 * K, d_ + 8192);                          \
    gload16(g0 + (size_t)128 * K, d_ + 16384);                        \
    gload16(g0 + (size_t)192 * K, d_ + 24576);                        \
  } while (0)

  f32x4 acc[8][4] = {};
  const int swz = (lrow & 7) << 4;
  const int k0b = (lk << 4) ^ swz;          // kk=0 byte within 128B row
  const int k1b = (64 + (lk << 4)) ^ swz;   // kk=1
  const int aBase = (wm * 128 + lrow) << 7;           // + m*2048
  const int bBase = ((wn * 64 + lrow) << 7) + 32768;  // + n*2048

  // ---- prologue: tile 0 fully staged
  STG4(0, 0); STG4(1, 0);
  asm volatile("s_waitcnt vmcnt(0)" ::: "memory");
  __builtin_amdgcn_s_barrier();

  for (int t = 0; t < nt; ++t) {
    const char* base = L + ((t & 1) << 16);
    bf16x8 aF[8], bF[4];
    if (t + 1 < nt) STG4(1, t + 1);            // B(t+1) -> buf^1 (early)
    // ---- kk0: 12 reads then 32 MFMA (counted lgkm overlaps them)
#pragma unroll
    for (int n = 0; n < 4; ++n) bF[n] = *(const bf16x8*)(base + bBase + n * 2048 + k0b);
#pragma unroll
    for (int m = 0; m < 8; ++m) aF[m] = *(const bf16x8*)(base + aBase + m * 2048 + k0b);
    __builtin_amdgcn_s_setprio(1);
#pragma unroll
    for (int m = 0; m < 8; ++m)
#pragma unroll
      for (int n = 0; n < 4; ++n)
        acc[m][n] = MFMA16(bF[n], aF[m], acc[m][n], 0, 0, 0);
    __builtin_amdgcn_s_setprio(0);
    if (t + 1 < nt) STG4(0, t + 1);            // A(t+1) -> buf^1
    // ---- kk1
#pragma unroll
    for (int n = 0; n < 4; ++n) bF[n] = *(const bf16x8*)(base + bBase + n * 2048 + k1b);
#pragma unroll
    for (int m = 0; m < 8; ++m) aF[m] = *(const bf16x8*)(base + aBase + m * 2048 + k1b);
    __builtin_amdgcn_s_setprio(1);
#pragma unroll
    for (int m = 0; m < 8; ++m)
#pragma unroll
      for (int n = 0; n < 4; ++n)
        acc[m][n] = MFMA16(bF[n], aF[m], acc[m][n], 0, 0, 0);
    __builtin_amdgcn_s_setprio(0);
    // ---- tile end: all my reads from buf done; my stages landed; sync
    asm volatile("s_waitcnt lgkmcnt(0)" ::: "memory");
    asm volatile("s_waitcnt vmcnt(0)" ::: "memory");
    __builtin_amdgcn_s_barrier();
  }
#undef STG4

  ushort_t* Cbz = Cb + (long long)blockIdx.z * pstr;
#pragma unroll
  for (int n = 0; n < 4; ++n) {
    int colb = n0 + wn * 64 + n * 16 + lk * 4;    // 4 consecutive cols
    int seg = colb >> 10;
    const float* bp = seg == 0 ? b0 : seg == 1 ? b1 : seg == 2 ? b2 : b3;
    float4 bv = *(const float4*)(bp + (colb & 1023));
    if (blockIdx.z != 0) { bv.x = bv.y = bv.z = bv.w = 0.f; }
#pragma unroll
    for (int m = 0; m < 8; ++m) {
      int row = m0 + wm * 128 + m * 16 + lrow;
      float v0 = acc[m][n][0] + bv.x, v1 = acc[m][n][1] + bv.y;
      float v2 = acc[m][n][2] + bv.z, v3 = acc[m][n][3] + bv.w;
      if (RELU) {
        v0 = fmaxf(v0, 0.f); v1 = fmaxf(v1, 0.f);
        v2 = fmaxf(v2, 0.f); v3 = fmaxf(v3, 0.f);
      }
      *(uint2*)&Cbz[(size_t)row * N + colb] = pk4(v0, v1, v2, v3);
    }
  }
}

// ---------------------------------------------------------------- attention
// R17-measured-best: R13 core + PAIRED STAGING (two 64-key tiles per
// __syncthreads). QBLK=128, swapped QK^T + swapped PV, T13 defer-max,
// complementary-qb causal balance. 80KB LDS, 2 blocks/CU.
template <int CAUSAL>
__global__ __launch_bounds__(256, 2) void attn_kernel(
    const ushort_t* __restrict__ Q, int ldq,
    const ushort_t* __restrict__ Kp, int ldk,
    const ushort_t* __restrict__ vT,  // [B*H,64,1024]
    const float* __restrict__ mask2,  // [B,1024] or null
    ushort_t* __restrict__ O) {       // [B*S,1024]
  __shared__ ushort_t sK[2][2][4096]; // [buf][sub][64key x 64dh] swizzled
  __shared__ ushort_t sV[2][2][4096]; // [buf][sub][64dh x 64key] swizzled
  __shared__ ushort_t sP[4][2048];    // per-wave [32 q][64 key] swizzled
  const int bh = blockIdx.x;
  const int yb = blockIdx.y;                    // 0..7
  const int qb = (yb < 4) ? yb : 11 - yb;       // complementary pairing
  const int b = bh >> 4, h = bh & 15;
  const int tid = threadIdx.x, w = tid >> 6, lane = tid & 63;
  const int lrow = lane & 15, lk = lane >> 4;
  const int q0 = qb * 128 + w * 32;   // wave's first q row (within seq)

  bf16x8 qF[2][2];
#pragma unroll
  for (int g = 0; g < 2; ++g) {
    const ushort_t* qptr =
        Q + (size_t)(b * 1024 + q0 + g * 16 + lrow) * ldq + h * 64 + lk * 8;
    qF[g][0] = *(const bf16x8*)qptr;
    qF[g][1] = *(const bf16x8*)(qptr + 32);
  }
  f32x4 oacc[2][4] = {};              // [g][t][j]: q=g*16+lrow, d=t*16+lk*4+j
  float m_[2] = {-3.0e38f, -3.0e38f}, l_[2] = {0.f, 0.f};  // per-lane q=lrow
  const int npair = CAUSAL ? (qb + 1) : 8;   // pairs of 64-key tiles
  const float C = 0.18033688011112042f;  // 0.125 * log2(e)

  const int sr = w * 16 + (lane >> 3);                  // staging row in 64
  const int scb = (((lane & 7) ^ (lane >> 3)) * 16);    // swizzled col byte
  const ushort_t* kbase = Kp + (size_t)(b * 1024 + sr) * ldk + h * 64 + (scb >> 1);
  const ushort_t* vbase = vT + ((size_t)bh * 64 + sr) * 1024 + (scb >> 1);
  char* dstK0 = (char*)sK[0][0] + w * 2048;  // HW adds lane*16
  char* dstV0 = (char*)sV[0][0] + w * 2048;

  // stage one 64-key tile (kb_ in 64-key units) into [bufi][subi]
#define STAGE(kb_, bufi, subi)                                          \
  do {                                                                  \
    const int off_ = (bufi) * 16384 + (subi) * 8192;                    \
    const ushort_t* gk = kbase + (size_t)(kb_) * 64 * ldk;              \
    gload16(gk, dstK0 + off_);                                          \
    gload16(gk + (size_t)8 * ldk, dstK0 + off_ + 1024);                 \
    const ushort_t* gv = vbase + (kb_) * 64;                            \
    gload16(gv, dstV0 + off_);                                          \
    gload16(gv + (size_t)8 * 1024, dstV0 + off_ + 1024);                \
  } while (0)

  STAGE(0, 0, 0); STAGE(1, 0, 1);
  const int swz = (lrow & 7) << 4;

  for (int kp = 0; kp < npair; ++kp) {
    const int buf = kp & 1;
    __syncthreads();                     // drains vmcnt: buf ready, buf^1 free
    if (kp + 1 < npair) { STAGE(2 * kp + 2, buf ^ 1, 0); STAGE(2 * kp + 3, buf ^ 1, 1); }

#pragma unroll
    for (int s = 0; s < 2; ++s) {
      const int kb = 2 * kp + s;
      const char* kB = (const char*)sK[buf][s];
      const char* vB = (const char*)sV[buf][s];
      // per-group causal tile classification (wave-uniform)
      bool skip[2], edge[2];
#pragma unroll
      for (int g = 0; g < 2; ++g) {
        int qming = q0 + g * 16;
        skip[g] = CAUSAL && (kb * 64 > qming + 15);
        edge[g] = CAUSAL && !skip[g] && (kb * 64 + 63 > qming);
      }
      if (CAUSAL && skip[0] && skip[1]) continue;
      // ---- QK^T swapped, K fragments shared across both q-groups
      f32x4 sc[2][4];
      __builtin_amdgcn_s_setprio(1);
#pragma unroll
      for (int kt = 0; kt < 4; ++kt) {
        const char* rp = kB + ((kt * 16 + lrow) << 7);
        bf16x8 k0 = *(const bf16x8*)(rp + ((lk * 16) ^ swz));
        bf16x8 k1 = *(const bf16x8*)(rp + ((64 + lk * 16) ^ swz));
        f32x4 z0 = {};
        z0 = MFMA16(k0, qF[0][0], z0, 0, 0, 0);
        sc[0][kt] = MFMA16(k1, qF[0][1], z0, 0, 0, 0);
        f32x4 z1 = {};
        z1 = MFMA16(k0, qF[1][0], z1, 0, 0, 0);
        sc[1][kt] = MFMA16(k1, qF[1][1], z1, 0, 0, 0);
      }
      __builtin_amdgcn_s_setprio(0);
      // ---- mask values (shared across groups: depend on key only)
      float4 mv[4];
      if (!CAUSAL) {
#pragma unroll
        for (int kt = 0; kt < 4; ++kt)
          mv[kt] = *(const float4*)&mask2[b * 1024 + kb * 64 + kt * 16 + lk * 4];
      }
      // ---- per-group softmax + P pack (lane-local, q = lrow)
#pragma unroll
      for (int g = 0; g < 2; ++g) {
        if (skip[g]) continue;
        if (CAUSAL) {
          if (edge[g]) {
            int qrel = q0 + g * 16 + lrow - kb * 64;
#pragma unroll
            for (int kt = 0; kt < 4; ++kt)
#pragma unroll
              for (int j = 0; j < 4; ++j)
                if (kt * 16 + lk * 4 + j > qrel) sc[g][kt][j] = -3.0e38f;
          }
        } else {
#pragma unroll
          for (int kt = 0; kt < 4; ++kt) {
            sc[g][kt][0] = fmaf(mv[kt].x, -8e9f, sc[g][kt][0]);
            sc[g][kt][1] = fmaf(mv[kt].y, -8e9f, sc[g][kt][1]);
            sc[g][kt][2] = fmaf(mv[kt].z, -8e9f, sc[g][kt][2]);
            sc[g][kt][3] = fmaf(mv[kt].w, -8e9f, sc[g][kt][3]);
          }
        }
        // max tree: nested triples -> v_max3, parallel sub-chains
        float a0 = fmaxf(fmaxf(sc[g][0][0], sc[g][0][1]), sc[g][0][2]);
        float a1 = fmaxf(fmaxf(sc[g][0][3], sc[g][1][0]), sc[g][1][1]);
        float a2 = fmaxf(fmaxf(sc[g][1][2], sc[g][1][3]), sc[g][2][0]);
        float a3 = fmaxf(fmaxf(sc[g][2][1], sc[g][2][2]), sc[g][2][3]);
        float a4 = fmaxf(fmaxf(sc[g][3][0], sc[g][3][1]), sc[g][3][2]);
        float pmax = fmaxf(fmaxf(fmaxf(a0, a1), fmaxf(a2, a3)),
                           fmaxf(a4, sc[g][3][3]));
        pmax = fmaxf(pmax, __shfl_xor(pmax, 16));
        pmax = fmaxf(pmax, __shfl_xor(pmax, 32));
        if (__any(pmax - m_[g] > 64.f)) {    // T13 defer-max
          float mnew = fmaxf(m_[g], pmax);
          float scale = __builtin_exp2f((m_[g] - mnew) * C);
          l_[g] *= scale;
          m_[g] = mnew;
#pragma unroll
          for (int t = 0; t < 4; ++t) {
            oacc[g][t][0] *= scale; oacc[g][t][1] *= scale;
            oacc[g][t][2] *= scale; oacc[g][t][3] *= scale;
          }
        }
        const float mC = m_[g] * C;
        float psk[4] = {0.f, 0.f, 0.f, 0.f};   // 4 parallel accumulators
#pragma unroll
        for (int kt = 0; kt < 4; ++kt)
#pragma unroll
          for (int j = 0; j < 4; ++j) {
            float e = __builtin_exp2f(fmaf(sc[g][kt][j], C, -mC));
            sc[g][kt][j] = e;
            psk[kt] += e;
          }
        float ps = (psk[0] + psk[1]) + (psk[2] + psk[3]);
        ps += __shfl_xor(ps, 16);
        ps += __shfl_xor(ps, 32);
        l_[g] += ps;
        char* bp = (char*)sP[w] + (g * 16 + lrow) * 128;
#pragma unroll
        for (int kt = 0; kt < 4; ++kt) {
          uint2 dd = pk4(sc[g][kt][0], sc[g][kt][1], sc[g][kt][2], sc[g][kt][3]);
          *(uint2*)(bp + ((kt * 32 + lk * 8) ^ swz)) = dd;
        }
      }
      // ---- PV swapped: oacc = mfma(vF, pF) -> d cols lane-local
      bf16x8 pF[2][2];
#pragma unroll
      for (int g = 0; g < 2; ++g) {
        if (skip[g]) continue;
        const char* pB = (const char*)sP[w] + (g * 16 + lrow) * 128;
        pF[g][0] = *(const bf16x8*)(pB + ((lk * 16) ^ swz));
        pF[g][1] = *(const bf16x8*)(pB + ((64 + lk * 16) ^ swz));
      }
      __builtin_amdgcn_s_setprio(1);
#pragma unroll
      for (int t = 0; t < 4; ++t) {
        const char* rp = vB + ((t * 16 + lrow) << 7);
        bf16x8 v0 = *(const bf16x8*)(rp + ((lk * 16) ^ swz));
        bf16x8 v1 = *(const bf16x8*)(rp + ((64 + lk * 16) ^ swz));
        if (!skip[0]) {
          oacc[0][t] = MFMA16(v0, pF[0][0], oacc[0][t], 0, 0, 0);
          oacc[0][t] = MFMA16(v1, pF[0][1], oacc[0][t], 0, 0, 0);
        }
        if (!skip[1]) {
          oacc[1][t] = MFMA16(v0, pF[1][0], oacc[1][t], 0, 0, 0);
          oacc[1][t] = MFMA16(v1, pF[1][1], oacc[1][t], 0, 0, 0);
        }
      }
      __builtin_amdgcn_s_setprio(0);
    }
  }
#undef STAGE
#pragma unroll
  for (int g = 0; g < 2; ++g) {
    float invl = 1.f / l_[g];           // q = lrow: lane-local, no shuffle
    int row = q0 + g * 16 + lrow;
    ushort_t* op = O + (size_t)(b * 1024 + row) * 1024 + h * 64;
#pragma unroll
    for (int t = 0; t < 4; ++t) {
      uint2 dd = pk4(oacc[g][t][0] * invl, oacc[g][t][1] * invl,
                     oacc[g][t][2] * invl, oacc[g][t][3] * invl);
      *(uint2*)&op[t * 16 + lk * 4] = dd;
    }
  }
}

// ---------------------------------------------------------------- layernorm
// y = LN(sum(bf16 partials) + residual) * g + beta
// RESBF: residual bf16 (else f32). WF32: write f32 (LN3) else bf16.
template <int RESBF, int NPART, int WF32>
__global__ __launch_bounds__(256) void ln_kernel(
    const ushort_t* __restrict__ p0, const ushort_t* __restrict__ p1,
    const ushort_t* __restrict__ p2, const ushort_t* __restrict__ p3,
    const void* __restrict__ rp,
    const float* __restrict__ g, const float* __restrict__ be,
    float* __restrict__ yf, ushort_t* __restrict__ yb) {
  int row = blockIdx.x, tid = threadIdx.x;
  size_t off = (size_t)row * 1024 + tid * 4;
  us4 a = *(const us4*)(p0 + off);
  float x0 = bf2f(a.x), x1 = bf2f(a.y), x2 = bf2f(a.z), x3 = bf2f(a.w);
  if (NPART >= 2) {
    us4 t = *(const us4*)(p1 + off);
    x0 += bf2f(t.x); x1 += bf2f(t.y); x2 += bf2f(t.z); x3 += bf2f(t.w);
  }
  if (NPART >= 4) {
    us4 t2 = *(const us4*)(p2 + off);
    us4 t3 = *(const us4*)(p3 + off);
    x0 += bf2f(t2.x) + bf2f(t3.x); x1 += bf2f(t2.y) + bf2f(t3.y);
    x2 += bf2f(t2.z) + bf2f(t3.z); x3 += bf2f(t2.w) + bf2f(t3.w);
  }
  if (RESBF) {
    us4 r = *(const us4*)((const ushort_t*)rp + off);
    x0 += bf2f(r.x); x1 += bf2f(r.y); x2 += bf2f(r.z); x3 += bf2f(r.w);
  } else {
    float4 r = *(const float4*)((const float*)rp + off);
    x0 += r.x; x1 += r.y; x2 += r.z; x3 += r.w;
  }
  float s = x0 + x1 + x2 + x3;
  float s2 = x0 * x0 + x1 * x1 + x2 * x2 + x3 * x3;
#pragma unroll
  for (int o = 1; o < 64; o <<= 1) { s += __shfl_xor(s, o); s2 += __shfl_xor(s2, o); }
  __shared__ float sh[8];
  if ((tid & 63) == 0) { sh[tid >> 6] = s; sh[4 + (tid >> 6)] = s2; }
  __syncthreads();
  s = sh[0] + sh[1] + sh[2] + sh[3];
  s2 = sh[4] + sh[5] + sh[6] + sh[7];
  float mu = s * 0.0009765625f;
  float var = s2 * 0.0009765625f - mu * mu;
  float inv = rsqrtf(var + 1e-6f);
  float4 gv = *(const float4*)(g + tid * 4);
  float4 bv = *(const float4*)(be + tid * 4);
  float y0 = (x0 - mu) * inv * gv.x + bv.x;
  float y1 = (x1 - mu) * inv * gv.y + bv.y;
  float y2 = (x2 - mu) * inv * gv.z + bv.z;
  float y3 = (x3 - mu) * inv * gv.w + bv.w;
  if (WF32) {
    *(float4*)(yf + off) = make_float4(y0, y1, y2, y3);
  } else {
    us4 o; o.x = f2bf(y0); o.y = f2bf(y1); o.z = f2bf(y2); o.w = f2bf(y3);
    *(us4*)(yb + off) = o;
  }
}

// ---------------------------------------------------------------- launcher
extern "C" void kernel_launch(void* const* d_in, const int* in_sizes, int n_in,
                              void* d_out, int out_size, void* d_ws, size_t ws_size,
                              hipStream_t stream) {
  (void)in_sizes; (void)n_in; (void)out_size; (void)ws_size;
  const float* inputs = (const float*)d_in[0];
  const float* enc    = (const float*)d_in[1];
  const float* mask2  = (const float*)d_in[3];
  const float* wq1 = (const float*)d_in[4];  const float* bq1 = (const float*)d_in[5];
  const float* wk1 = (const float*)d_in[6];  const float* bk1 = (const float*)d_in[7];
  const float* wv1 = (const float*)d_in[8];  const float* bv1 = (const float*)d_in[9];
  const float* wo1 = (const float*)d_in[10]; const float* bo1 = (const float*)d_in[11];
  const float* wq2 = (const float*)d_in[12]; const float* bq2 = (const float*)d_in[13];
  const float* wk2 = (const float*)d_in[14]; const float* bk2 = (const float*)d_in[15];
  const float* wv2 = (const float*)d_in[16]; const float* bv2 = (const float*)d_in[17];
  const float* wo2 = (const float*)d_in[18]; const float* bo2 = (const float*)d_in[19];
  const float* wff1 = (const float*)d_in[20]; const float* bff1 = (const float*)d_in[21];
  const float* wff2 = (const float*)d_in[22]; const float* bff2 = (const float*)d_in[23];
  const float* g1 = (const float*)d_in[24]; const float* be1 = (const float*)d_in[25];
  const float* g2 = (const float*)d_in[26]; const float* be2 = (const float*)d_in[27];
  const float* g3 = (const float*)d_in[28]; const float* be3 = (const float*)d_in[29];

  char* ws = (char*)d_ws;
  const size_t MB = 1024 * 1024;
  const size_t W1M = 1048576;  // elements per 1024x1024 weight
  // --- workspace map (liveness verified per stream order) ---
  ushort_t* wt    = (ushort_t*)ws;              // 0..32MB  bf16 W^T
  ushort_t* xb    = (ushort_t*)(ws + 32 * MB);  // 32..40   input bf16 (dead after QKV)
  ushort_t* encb  = (ushort_t*)(ws + 40 * MB);  // 40..48   enc bf16 (dead after KV2)
  ushort_t* qkvb  = (ushort_t*)(ws + 48 * MB);  // 48..72   QKV (dead after attn1)
  ushort_t* vtb   = (ushort_t*)(ws + 72 * MB);  // 72..80   vT (per attention)
  ushort_t* attnb = (ushort_t*)(ws + 80 * MB);  // 80..88   attn out bf16
  ushort_t* y1b   = (ushort_t*)(ws + 88 * MB);  // 88..96   LN1 out (Q2 A + LN2 residual)
  ushort_t* y2b   = (ushort_t*)(ws + 96 * MB);  // 96..104  LN2 out (FFN1 A + LN3 residual)
  ushort_t* cp    = (ushort_t*)(ws + 104 * MB); // 104..120 split-K bf16 partials (2x8MB)
  ushort_t* q2b   = (ushort_t*)(ws + 32 * MB);  // 32..40   Q2 bf16 (over dead xb)
  ushort_t* kv2b  = (ushort_t*)(ws + 56 * MB);  // 56..72   KV2 (dead after attn2)
  ushort_t* hb    = (ushort_t*)(ws + 32 * MB);  // 32..64   FFN hidden (after attn2)
  ushort_t* pp    = (ushort_t*)(ws + 104 * MB); // 104..136 FF2 partials 4x8MB
  float* outf = (float*)d_out;
  const long long PE = 4LL * 1024 * 1024;  // elements per 8MB bf16 partial

  // prep: fused casts + weight transposes
  cast2_bf16_kernel<<<8192, 256, 0, stream>>>(inputs, xb, enc, encb);
  Src8 s8; s8.p[0] = wq1; s8.p[1] = wk1; s8.p[2] = wv1; s8.p[3] = wo1;
           s8.p[4] = wq2; s8.p[5] = wk2; s8.p[6] = wv2; s8.p[7] = wo2;
  transpose_cast8_kernel<<<dim3(16, 16, 8), 256, 0, stream>>>(s8, wt);
  transpose_cast_kernel<<<dim3(64, 16), 256, 0, stream>>>(wff1, wt + 8 * W1M, 1024, 4096);
  transpose_cast_kernel<<<dim3(16, 64), 256, 0, stream>>>(wff2, wt + 12 * W1M, 4096, 1024);

  // ---- self-attention
  gemm256<0><<<dim3(16, 12, 1), 512, 131072, stream>>>(
      xb, wt, bq1, bk1, bv1, bv1, qkvb, 4096, 3072, 1024, 1024, 0);
  transpose_v_kernel<<<dim3(16, 64), 256, 0, stream>>>(qkvb + 2048, 3072, vtb);
  attn_kernel<1><<<dim3(64, 8), 256, 0, stream>>>(
      qkvb, 3072, qkvb + 1024, 3072, vtb, nullptr, attnb);
  gemm_bt<0><<<dim3(32, 8, 2), 256, 0, stream>>>(                // split-K=2
      attnb, wt + 3 * W1M, bo1, bo1, bo1, bo1, cp, 4096, 1024, 1024, 512, PE);
  ln_kernel<0, 2, 0><<<4096, 256, 0, stream>>>(cp, cp + PE, nullptr, nullptr,
                                               inputs, g1, be1, nullptr, y1b);

  // ---- cross-attention
  gemm_bt<0><<<dim3(32, 8, 2), 256, 0, stream>>>(                // Q2 split-K=2
      y1b, wt + 4 * W1M, bq2, bq2, bq2, bq2, cp, 4096, 1024, 1024, 512, PE);
  reduce_cast_kernel<<<4096, 256, 0, stream>>>(cp, cp + PE, q2b, 1048576);
  gemm_bt<0><<<dim3(32, 16, 1), 256, 0, stream>>>(
      encb, wt + 5 * W1M, bk2, bv2, bk2, bk2, kv2b, 4096, 2048, 1024, 1024, 0);
  transpose_v_kernel<<<dim3(16, 64), 256, 0, stream>>>(kv2b + 1024, 2048, vtb);
  attn_kernel<0><<<dim3(64, 8), 256, 0, stream>>>(
      q2b, 1024, kv2b, 2048, vtb, mask2, attnb);
  gemm_bt<0><<<dim3(32, 8, 2), 256, 0, stream>>>(                // split-K=2
      attnb, wt + 7 * W1M, bo2, bo2, bo2, bo2, cp, 4096, 1024, 1024, 512, PE);
  ln_kernel<1, 2, 0><<<4096, 256, 0, stream>>>(cp, cp + PE, nullptr, nullptr,
                                               y1b, g2, be2, nullptr, y2b);

  // ---- FFN
  gemm256<1><<<dim3(16, 16, 1), 512, 131072, stream>>>(
      y2b, wt + 8 * W1M, bff1, bff1 + 1024, bff1 + 2048, bff1 + 3072,
      hb, 4096, 4096, 1024, 1024, 0);
  gemm256<0><<<dim3(16, 4, 4), 512, 131072, stream>>>(           // FF2 split-K=4
      hb, wt + 12 * W1M, bff2, bff2, bff2, bff2, pp, 4096, 1024, 4096, 1024, PE);
  ln_kernel<1, 4, 1><<<4096, 256, 0, stream>>>(pp, pp + PE, pp + 2 * PE, pp + 3 * PE,
                                               y2b, g3, be3, outf, nullptr);
}